// Round 7
// baseline (671.183 us; speedup 1.0000x reference)
//
#include <hip/hip_runtime.h>
#include <stdint.h>

typedef int i32x4  __attribute__((ext_vector_type(4)));
typedef int i32x16 __attribute__((ext_vector_type(16)));

constexpr int C     = 256;           // channels
constexpr int H     = 28, W = 28;
constexpr int HW    = H * W;         // 784
constexpr int NB    = 64;            // batch
constexpr int CNT   = NB * HW;       // BN reduction count = 50176
constexpr int TOTAL = NB * C * HW;   // 12,845,056
constexpr int PP    = 30 * 30;       // zero-padded pixel count (30x30)

// ---------------------------------------------------------------------------
// Pack x -> i8 signs, channel-last, zero-padded spatial border:
//   a1[n][(oh+1)*30 + ow+1][ci] = sign(x[n][ci][oh*W+ow])
// LDS 64x64 transpose so both global read (lanes along p) and write (lanes
// along c) are coalesced. Border stays 0 from the memset: 0 contributes 0 to
// the i8 MFMA dot product — the zero-padding is EXACT, no correction needed.
// ---------------------------------------------------------------------------
__global__ void pack_x_t(const float* __restrict__ x, int8_t* __restrict__ a1) {
    __shared__ float tile[64][65];
    const int b = blockIdx.x;              // 64n * 4cc * 13pc
    const int n = b / 52, r = b % 52, cc = r / 13, pc = r % 13;
    const int c0 = cc * 64, p0 = pc * 64;
    const int lane = threadIdx.x & 63, grp = threadIdx.x >> 6;
#pragma unroll
    for (int i = 0; i < 16; ++i) {
        const int c = grp * 16 + i, p = p0 + lane;
        tile[c][lane] = (p < HW) ? x[((size_t)n * C + c0 + c) * HW + p] : 0.f;
    }
    __syncthreads();
#pragma unroll
    for (int i = 0; i < 16; ++i) {
        const int p = p0 + grp * 16 + i;
        if (p < HW) {
            const float v = tile[lane][grp * 16 + i];
            const int q = (p / W + 1) * 30 + (p % W) + 1;
            a1[((size_t)n * PP + q) * C + c0 + lane] = (v < 0.f) ? -1 : 1;
        }
    }
}

// ---------------------------------------------------------------------------
// Pack weights -> i8 signs: wb[co][tap][ci] = sign(w[co][ci][tap])   (OIHW in)
// ---------------------------------------------------------------------------
__global__ void pack_w_i8(const float* __restrict__ w, int8_t* __restrict__ wb) {
    const int co = blockIdx.x, ci = threadIdx.x;
    const float* src = w + ((size_t)co * C + ci) * 9;
#pragma unroll
    for (int tap = 0; tap < 9; ++tap)
        wb[((size_t)co * 9 + tap) * C + ci] = (src[tap] < 0.f) ? -1 : 1;
}

__device__ inline i32x16 z16() { i32x16 v; for (int i = 0; i < 16; ++i) v[i] = 0; return v; }

// ---------------------------------------------------------------------------
// Binary conv as i8 MFMA GEMM.  Per wave: M=64 pixels x N=64 co, K = 9 taps
// x 256 ci -> 72x mfma_i32_32x32x32_i8 into 4 acc frags.  A and B read
// straight from global (both L2-resident; the 4 waves of a block share the
// same A addresses -> L1 hits).  A rows: lane%32 = pixel, lane/32 = k-half;
// B cols: lane%32 = co, same k-half convention -> any k-permutation error
// cancels between A and B by construction.
// C/D frag (HW-verified): col = lane&31, row = (reg&3) + 8*(reg>>2) + 4*(lane>>5).
// SECOND=false (conv1): store y1 [n][p][co] i16 + per-channel stats.
// SECOND=true  (conv2): LDS-transpose tile -> c2t NCHW i16, fuse residual
//                       read (lanes along p, coalesced) + BN2 stats.
// ---------------------------------------------------------------------------
template<bool SECOND>
__launch_bounds__(256)
__global__ void conv_mfma(const int8_t* __restrict__ A, const int8_t* __restrict__ Bw,
                          const float* __restrict__ xres,
                          short* __restrict__ yout,
                          double* __restrict__ sum, double* __restrict__ sumsq) {
    __shared__ short tr[4][64 * 66];
    const int lane = threadIdx.x & 63, widx = threadIdx.x >> 6;
    const int wid = blockIdx.x * 4 + widx;          // 3328 wave-tiles total
    const int n = wid / 52, rr = wid % 52, mt = rr >> 2, nt = rr & 3;
    const int p0 = mt * 64, co0 = nt * 64;
    const int l31 = lane & 31, kh2 = lane >> 5;

    int pA0 = p0 + l31;      if (pA0 > HW - 1) pA0 = HW - 1;   // clamp: garbage rows
    int pA1 = p0 + 32 + l31; if (pA1 > HW - 1) pA1 = HW - 1;   // masked at store
    const int oh0 = pA0 / W, ow0 = pA0 % W, oh1 = pA1 / W, ow1 = pA1 % W;

    const int8_t* An = A + (size_t)n * PP * C + kh2 * 16;
    const int8_t* B0 = Bw + (size_t)(co0 + l31) * 9 * C + kh2 * 16;
    const int8_t* B1 = B0 + (size_t)32 * 9 * C;

    i32x16 acc00 = z16(), acc01 = z16(), acc10 = z16(), acc11 = z16();

#pragma unroll 1
    for (int tap = 0; tap < 9; ++tap) {
        const int kh = tap / 3, kw = tap - kh * 3;
        const int8_t* pa0 = An + (size_t)((oh0 + kh) * 30 + ow0 + kw) * C;
        const int8_t* pa1 = An + (size_t)((oh1 + kh) * 30 + ow1 + kw) * C;
        const int8_t* pb0 = B0 + tap * C;
        const int8_t* pb1 = B1 + tap * C;
#pragma unroll
        for (int kc = 0; kc < 8; ++kc) {
            const i32x4 af0 = *(const i32x4*)(pa0 + kc * 32);
            const i32x4 af1 = *(const i32x4*)(pa1 + kc * 32);
            const i32x4 bf0 = *(const i32x4*)(pb0 + kc * 32);
            const i32x4 bf1 = *(const i32x4*)(pb1 + kc * 32);
            acc00 = __builtin_amdgcn_mfma_i32_32x32x32_i8(af0, bf0, acc00, 0, 0, 0);
            acc01 = __builtin_amdgcn_mfma_i32_32x32x32_i8(af0, bf1, acc01, 0, 0, 0);
            acc10 = __builtin_amdgcn_mfma_i32_32x32x32_i8(af1, bf0, acc10, 0, 0, 0);
            acc11 = __builtin_amdgcn_mfma_i32_32x32x32_i8(af1, bf1, acc11, 0, 0, 0);
        }
    }

    if constexpr (!SECOND) {
        // y1 channel-last: per reg, lanes 0-31 -> co consecutive (coalesced i16)
#pragma unroll
        for (int ns = 0; ns < 2; ++ns) {
            float s1 = 0.f, s2 = 0.f;
            const int co = co0 + ns * 32 + l31;
#pragma unroll
            for (int ms = 0; ms < 2; ++ms) {
#pragma unroll
                for (int reg = 0; reg < 16; ++reg) {
                    const int row = (reg & 3) + 8 * (reg >> 2) + 4 * kh2;
                    const int p = p0 + ms * 32 + row;
                    const int v = (ms == 0 ? (ns == 0 ? acc00 : acc01)
                                           : (ns == 0 ? acc10 : acc11))[reg];
                    if (p < HW) {
                        yout[((size_t)n * HW + p) * C + co] = (short)v;
                        s1 += (float)v;
                        s2 += (float)v * (float)v;
                    }
                }
            }
            // lanes l and l+32 hold the same co (different rows): fold, then atomic
            s1 += __shfl_down(s1, 32);
            s2 += __shfl_down(s2, 32);
            if (lane < 32) {
                atomicAdd(&sum[co0 + ns * 32 + lane], (double)s1);
                atomicAdd(&sumsq[co0 + ns * 32 + lane], (double)s2);
            }
        }
    } else {
        // stage the 64x64 tile in LDS (stride 66 shorts: conflict-free both ways)
        short* T = &tr[widx][0];
#pragma unroll
        for (int ns = 0; ns < 2; ++ns)
#pragma unroll
            for (int ms = 0; ms < 2; ++ms)
#pragma unroll
                for (int reg = 0; reg < 16; ++reg) {
                    const int row = (reg & 3) + 8 * (reg >> 2) + 4 * kh2;
                    const int v = (ms == 0 ? (ns == 0 ? acc00 : acc01)
                                           : (ns == 0 ? acc10 : acc11))[reg];
                    T[(ns * 32 + l31) * 66 + ms * 32 + row] = (short)v;
                }
        __syncthreads();
        // read back transposed: lane = pixel -> NCHW stores and x-residual
        // reads are both coalesced.  Stats use z = (float)c2 + x, the exact
        // same float op bn_clip_add recomputes -> stats/output consistent.
        const int p = p0 + lane;
        const bool valid = p < HW;
        const float* xn = xres + (size_t)n * C * HW;
#pragma unroll 1
        for (int co_l = 0; co_l < 64; ++co_l) {
            const int co = co0 + co_l;
            const short cv = T[co_l * 66 + lane];
            float z = 0.f;
            if (valid) {
                yout[((size_t)n * C + co) * HW + p] = cv;     // c2t NCHW (no residual: exact i16)
                z = (float)cv + xn[(size_t)co * HW + p];
            }
            float s1 = z, s2 = z * z;
#pragma unroll
            for (int off = 32; off; off >>= 1) {
                s1 += __shfl_down(s1, off);
                s2 += __shfl_down(s2, off);
            }
            if (lane == 0) {
                atomicAdd(&sum[co], (double)s1);
                atomicAdd(&sumsq[co], (double)s2);
            }
        }
    }
}

// ---------------------------------------------------------------------------
// BN stats -> per-channel scale/shift (fp64 internally)
// ---------------------------------------------------------------------------
__global__ void finalize_kernel(const double* __restrict__ sum,
                                const double* __restrict__ sumsq,
                                const float* __restrict__ gamma,
                                const float* __restrict__ beta,
                                float* __restrict__ scale,
                                float* __restrict__ shift) {
    const int c = threadIdx.x;
    const double mean = sum[c] / (double)CNT;
    const double var  = sumsq[c] / (double)CNT - mean * mean;
    const double inv  = 1.0 / sqrt(var + 1e-5);
    scale[c] = (float)inv * gamma[c];
    shift[c] = beta[c] - (float)(mean * inv) * gamma[c];
}

// ---------------------------------------------------------------------------
// BN1 + hardtanh + binarize -> a2 i8 (padded channel-last).  sign(clip(z)) ==
// sign(z).  y1 is channel-last so everything is lane-coalesced; short4/char4.
// ---------------------------------------------------------------------------
__global__ void bn_sign(const short* __restrict__ y1, const float* __restrict__ scale,
                        const float* __restrict__ shift, int8_t* __restrict__ a2) {
    const int i4 = blockIdx.x * 256 + threadIdx.x;   // quad over TOTAL/4 (exact grid)
    const short4 yv = ((const short4*)y1)[i4];
    const int e = i4 * 4;
    const int c = e & 255;                 // channel-last: 4 consecutive co
    const int np = e >> 8;                 // n*HW + p
    const int n = np / HW, p = np % HW;
    const int q = (p / W + 1) * 30 + (p % W) + 1;
    char4 o;
    o.x = ((float)yv.x * scale[c + 0] + shift[c + 0] < 0.f) ? -1 : 1;
    o.y = ((float)yv.y * scale[c + 1] + shift[c + 1] < 0.f) ? -1 : 1;
    o.z = ((float)yv.z * scale[c + 2] + shift[c + 2] < 0.f) ? -1 : 1;
    o.w = ((float)yv.w * scale[c + 3] + shift[c + 3] < 0.f) ? -1 : 1;
    ((char4*)a2)[(((size_t)n * PP + q) * C + c) >> 2] = o;
}

// ---------------------------------------------------------------------------
// Final: out = clip((c2 + x)*scale + shift, -1, 1), all NCHW, float4/short4.
// ---------------------------------------------------------------------------
__global__ void bn_clip_add(const short* __restrict__ c2t, const float* __restrict__ x,
                            const float* __restrict__ scale, const float* __restrict__ shift,
                            float* __restrict__ out) {
    const int i4 = blockIdx.x * 256 + threadIdx.x;   // TOTAL/4, exact grid
    const short4 cv = ((const short4*)c2t)[i4];
    const float4 xv = ((const float4*)x)[i4];
    const int c = (i4 / 196) & 255;                  // HW/4 = 196, no c-crossing
    const float s = scale[c], b = shift[c];
    float4 o;
    o.x = fminf(1.f, fmaxf(-1.f, ((float)cv.x + xv.x) * s + b));
    o.y = fminf(1.f, fmaxf(-1.f, ((float)cv.y + xv.y) * s + b));
    o.z = fminf(1.f, fmaxf(-1.f, ((float)cv.z + xv.z) * s + b));
    o.w = fminf(1.f, fmaxf(-1.f, ((float)cv.w + xv.w) * s + b));
    ((float4*)out)[i4] = o;
}

// ---------------------------------------------------------------------------
extern "C" void kernel_launch(void* const* d_in, const int* in_sizes, int n_in,
                              void* d_out, int out_size, void* d_ws, size_t ws_size,
                              hipStream_t stream) {
    const float* x  = (const float*)d_in[0];
    const float* w1 = (const float*)d_in[1];
    const float* w2 = (const float*)d_in[2];
    const float* g1 = (const float*)d_in[3];
    const float* b1 = (const float*)d_in[4];
    const float* g2 = (const float*)d_in[5];
    const float* b2 = (const float*)d_in[6];

    char* ws = (char*)d_ws;
    size_t off = 0;
    int8_t* a1  = (int8_t*)(ws + off); off += (size_t)NB * PP * C;   // 14.75 MB
    int8_t* a2  = (int8_t*)(ws + off); off += (size_t)NB * PP * C;   // adjacent: one memset
    int8_t* wb1 = (int8_t*)(ws + off); off += (size_t)C * 9 * C;     // 0.59 MB
    int8_t* wb2 = (int8_t*)(ws + off); off += (size_t)C * 9 * C;
    short*  c2t = (short*)(ws + off);  off += (size_t)TOTAL * 2;     // 25.7 MB
    double* stats = (double*)(ws + off); off += 4 * 256 * 8;
    double *sum1 = stats, *sumsq1 = stats + 256, *sum2 = stats + 512, *sumsq2 = stats + 768;
    float* coefs = (float*)(ws + off); off += 4 * 256 * 4;
    float *scale1 = coefs, *shift1 = coefs + 256, *scale2 = coefs + 512, *shift2 = coefs + 768;

    short* y1 = (short*)d_out;   // y1 i16 channel-last lives in d_out; dead before final write

    hipMemsetAsync(a1, 0, 2 * (size_t)NB * PP * C, stream);  // zero padded borders (exact)
    hipMemsetAsync(stats, 0, 4 * 256 * 8, stream);

    pack_w_i8<<<256, 256, 0, stream>>>(w1, wb1);
    pack_w_i8<<<256, 256, 0, stream>>>(w2, wb2);
    pack_x_t<<<64 * 52, 256, 0, stream>>>(x, a1);

    conv_mfma<false><<<832, 256, 0, stream>>>(a1, wb1, nullptr, y1, sum1, sumsq1);
    finalize_kernel<<<1, 256, 0, stream>>>(sum1, sumsq1, g1, b1, scale1, shift1);
    bn_sign<<<TOTAL / 4 / 256, 256, 0, stream>>>(y1, scale1, shift1, a2);
    conv_mfma<true><<<832, 256, 0, stream>>>(a2, wb2, x, c2t, sum2, sumsq2);
    finalize_kernel<<<1, 256, 0, stream>>>(sum2, sumsq2, g2, b2, scale2, shift2);
    bn_clip_add<<<TOTAL / 4 / 256, 256, 0, stream>>>(c2t, x, scale2, shift2, (float*)d_out);
}